// Round 1
// baseline (23795.903 us; speedup 1.0000x reference)
//
#include <hip/hip_runtime.h>

#define C 192
#define T 4096
#define KS 5
#define TT 32
#define L 16
#define BATCH 16

#define XS_STRIDE (TT + 4)   // 36: x tile with halo of 2 each side
#define AS_STRIDE (TT + 1)   // 33: acts tile, padded

// One fused WaveNet layer:
//   x_in = conv_K5(x, Wc) + bc            (C -> 2C)
//   acts = tanh(x_in[:C]) * sigmoid(x_in[C:])
//   rs   = conv_1x1(acts, Wr) + br        (C -> 2C, or C -> C if LAST)
//   if !LAST: x_out = (x + rs[:C]) * mask ; o (+)= rs[C:]
//   if  LAST: o = (o + rs) * mask
template<bool FIRST, bool LAST>
__global__ __launch_bounds__(256)
void wavenet_layer(const float* __restrict__ xin,
                   float* __restrict__ xout,
                   const float* __restrict__ mask,
                   const float* __restrict__ Wc,   // (2C, C, KS)
                   const float* __restrict__ bc,   // (2C)
                   const float* __restrict__ Wr,   // (2C or C, C)
                   const float* __restrict__ br,   // (2C or C)
                   float* __restrict__ o)          // (B, C, T)
{
    __shared__ float xs[C][XS_STRIDE];
    __shared__ float as[C][AS_STRIDE];

    const int tid = threadIdx.x;
    const int tx  = tid & 7;    // t sub-tile: 4 positions each
    const int ty  = tid >> 3;   // 0..31: out-channel group
    const int t0  = blockIdx.x * TT;
    const int b   = blockIdx.y;

    // ---- stage x tile (with halo, zero-padded at sequence edges) ----
    const float* xb = xin + (size_t)b * C * T;
    for (int idx = tid; idx < C * XS_STRIDE; idx += 256) {
        int ic = idx / XS_STRIDE;
        int tt = idx - ic * XS_STRIDE;
        int t  = t0 - 2 + tt;
        xs[ic][tt] = (t >= 0 && t < T) ? xb[(size_t)ic * T + t] : 0.f;
    }
    __syncthreads();

    const int p0 = tx * 4;

    // ---- K=5 conv, C -> 2C; thread covers oc = ty + 32*j, j=0..11 ----
    float acc[12][4];
    #pragma unroll
    for (int j = 0; j < 12; ++j) {
        float bv = bc[ty + 32 * j];
        #pragma unroll
        for (int q = 0; q < 4; ++q) acc[j][q] = bv;
    }
    for (int ic = 0; ic < C; ++ic) {
        float xv[8];
        #pragma unroll
        for (int q = 0; q < 8; ++q) xv[q] = xs[ic][p0 + q];
        #pragma unroll
        for (int j = 0; j < 12; ++j) {
            const float* wj = Wc + ((size_t)(ty + 32 * j) * C + ic) * KS;
            #pragma unroll
            for (int k = 0; k < KS; ++k) {
                float wv = wj[k];
                #pragma unroll
                for (int q = 0; q < 4; ++q)
                    acc[j][q] = fmaf(wv, xv[q + k], acc[j][q]);
            }
        }
    }

    // ---- gating: channel c = ty+32j pairs acc[j] (tanh) with acc[j+6] (sigmoid)
    #pragma unroll
    for (int j = 0; j < 6; ++j) {
        int c = ty + 32 * j;
        #pragma unroll
        for (int q = 0; q < 4; ++q) {
            float x1 = acc[j][q];
            float x2 = acc[j + 6][q];
            float ax = fabsf(x1);
            float e  = __expf(-2.f * ax);            // in (0,1], no overflow
            float th = (1.f - e) / (1.f + e);
            th = copysignf(th, x1);
            float sg = 1.f / (1.f + __expf(-x2));    // safe at both tails
            as[c][p0 + q] = th * sg;
        }
    }
    __syncthreads();

    // ---- 1x1 conv on acts ----
    constexpr int NJ = LAST ? 6 : 12;
    float acc2[NJ][4];
    #pragma unroll
    for (int j = 0; j < NJ; ++j) {
        float bv = br[ty + 32 * j];
        #pragma unroll
        for (int q = 0; q < 4; ++q) acc2[j][q] = bv;
    }
    for (int ic = 0; ic < C; ++ic) {
        float av[4];
        #pragma unroll
        for (int q = 0; q < 4; ++q) av[q] = as[ic][p0 + q];
        #pragma unroll
        for (int j = 0; j < NJ; ++j) {
            float wv = Wr[(size_t)(ty + 32 * j) * C + ic];
            #pragma unroll
            for (int q = 0; q < 4; ++q)
                acc2[j][q] = fmaf(wv, av[q], acc2[j][q]);
        }
    }

    const float* mb = mask + (size_t)b * T;
    float mv[4];
    #pragma unroll
    for (int q = 0; q < 4; ++q) mv[q] = mb[t0 + p0 + q];

    if (LAST) {
        #pragma unroll
        for (int j = 0; j < 6; ++j) {
            int c = ty + 32 * j;
            float* op = o + ((size_t)b * C + c) * T + t0 + p0;
            #pragma unroll
            for (int q = 0; q < 4; ++q)
                op[q] = (op[q] + acc2[j][q]) * mv[q];
        }
    } else {
        #pragma unroll
        for (int j = 0; j < 6; ++j) {
            int c = ty + 32 * j;
            // residual x update (masked)
            float* xp = xout + ((size_t)b * C + c) * T + t0 + p0;
            #pragma unroll
            for (int q = 0; q < 4; ++q)
                xp[q] = (xs[c][p0 + 2 + q] + acc2[j][q]) * mv[q];
            // skip accumulation
            float* op = o + ((size_t)b * C + c) * T + t0 + p0;
            #pragma unroll
            for (int q = 0; q < 4; ++q) {
                if (FIRST) op[q] = acc2[j + 6][q];
                else       op[q] += acc2[j + 6][q];
            }
        }
    }
}

extern "C" void kernel_launch(void* const* d_in, const int* in_sizes, int n_in,
                              void* d_out, int out_size, void* d_ws, size_t ws_size,
                              hipStream_t stream)
{
    const float* x      = (const float*)d_in[0];
    const float* mask   = (const float*)d_in[1];
    const float* W_in   = (const float*)d_in[2];
    const float* b_in   = (const float*)d_in[3];
    const float* W_rs   = (const float*)d_in[4];
    const float* b_rs   = (const float*)d_in[5];
    const float* W_last = (const float*)d_in[6];
    const float* b_last = (const float*)d_in[7];
    float* o = (float*)d_out;

    const size_t xelems = (size_t)BATCH * C * T;
    float* xa = (float*)d_ws;
    float* xb = (float*)((char*)d_ws + xelems * sizeof(float));

    dim3 grid(T / TT, BATCH);
    dim3 block(256);

    // layer 0: reads original x, stores o (no accumulate -> no memset needed)
    wavenet_layer<true, false><<<grid, block, 0, stream>>>(
        x, xa, mask,
        W_in, b_in, W_rs, b_rs, o);

    const float* cur = xa;
    for (int i = 1; i < L - 1; ++i) {
        float* nxt = (i & 1) ? xb : xa;
        wavenet_layer<false, false><<<grid, block, 0, stream>>>(
            cur, nxt, mask,
            W_in + (size_t)i * 2 * C * C * KS, b_in + (size_t)i * 2 * C,
            W_rs + (size_t)i * 2 * C * C,      b_rs + (size_t)i * 2 * C,
            o);
        cur = nxt;
    }
    // last layer: 1x1 conv with W_last (C->C), o = (o + rs) * mask
    wavenet_layer<false, true><<<grid, block, 0, stream>>>(
        cur, nullptr, mask,
        W_in + (size_t)(L - 1) * 2 * C * C * KS, b_in + (size_t)(L - 1) * 2 * C,
        W_last, b_last, o);
}

// Round 4
// 5560.392 us; speedup vs baseline: 4.2795x; 4.2795x over previous
//
#include <hip/hip_runtime.h>
#include <hip/hip_bf16.h>
#include <type_traits>

#define C 192
#define T 4096
#define L 16
#define BATCH 16
#define NT 64          // t-positions per block
#define XR 68          // x tile rows incl. halo 2+2
#define CPAD 200       // padded channel stride in LDS

typedef __attribute__((ext_vector_type(8))) short short8;
typedef __attribute__((ext_vector_type(4))) float f32x4;

__device__ __forceinline__ short f2bf(float v) {
    __hip_bfloat16 h = __float2bfloat16(v);
    return *reinterpret_cast<const short*>(&h);
}
__device__ __forceinline__ float bf2f(short s) {
    unsigned u = ((unsigned)(unsigned short)s) << 16;
    float f;
    __builtin_memcpy(&f, &u, 4);
    return f;
}
__device__ __forceinline__ float xld(float v)  { return v; }
__device__ __forceinline__ float xld(short v)  { return bf2f(v); }

__device__ __forceinline__ float gatefn(float x1, float x2) {
    float ax = fabsf(x1);
    float e  = __expf(-2.f * ax);
    float th = __builtin_copysignf((1.f - e) / (1.f + e), x1);
    float sg = 1.f / (1.f + __expf(-x2));
    return th * sg;
}

// ---- weight pre-format with hi/lo bf16 split (Dekker: v-hi exact in fp32) ----
// gid = ((((l*5+tap)*24+mt)*6+icc)*64+lane); oc = mt*16+(lane&15), ic = icc*32+(lane>>4)*8+i
__global__ __launch_bounds__(256)
void fmt_win(const float* __restrict__ W, short* __restrict__ dhi,
             short* __restrict__ dlo, int total) {
    int gid = blockIdx.x * 256 + threadIdx.x;
    if (gid >= total) return;
    int lane = gid & 63; int r = gid >> 6;
    int icc = r % 6; r /= 6;
    int mt  = r % 24; r /= 24;
    int tap = r % 5;  int l = r / 5;
    int oc  = mt * 16 + (lane & 15);
    int ic0 = icc * 32 + (lane >> 4) * 8;
    const float* s = W + ((size_t)((l * 384 + oc) * 192 + ic0)) * 5 + tap;
    short8 vh, vl;
    #pragma unroll
    for (int i = 0; i < 8; ++i) {
        float v = s[(size_t)i * 5];
        short h = f2bf(v);
        vh[i] = h;
        vl[i] = f2bf(v - bf2f(h));
    }
    *reinterpret_cast<short8*>(dhi + (size_t)gid * 8) = vh;
    *reinterpret_cast<short8*>(dlo + (size_t)gid * 8) = vl;
}

// 1x1 weights: gid = ((l*mtc+mt)*6+icc)*64+lane
__global__ __launch_bounds__(256)
void fmt_w11(const float* __restrict__ W, short* __restrict__ dhi,
             short* __restrict__ dlo, int mtc, int total) {
    int gid = blockIdx.x * 256 + threadIdx.x;
    if (gid >= total) return;
    int lane = gid & 63; int r = gid >> 6;
    int icc = r % 6; r /= 6;
    int mt  = r % mtc; int l = r / mtc;
    int oc  = mt * 16 + (lane & 15);
    int ic0 = icc * 32 + (lane >> 4) * 8;
    const float* s = W + (size_t)(l * (mtc * 16) + oc) * 192 + ic0;
    short8 vh, vl;
    #pragma unroll
    for (int i = 0; i < 8; ++i) {
        float v = s[i];
        short h = f2bf(v);
        vh[i] = h;
        vl[i] = f2bf(v - bf2f(h));
    }
    *reinterpret_cast<short8*>(dhi + (size_t)gid * 8) = vh;
    *reinterpret_cast<short8*>(dlo + (size_t)gid * 8) = vl;
}

// ---- fused WaveNet layer, split-bf16 precision on conv AND 1x1 ----
// 8 waves: wm=wid&3 (3 mt-pairs each), wn=wid>>2 (2 nt-tiles each)
// After the conv, xhi/xlo LDS is reused for the acts hi/lo tiles.
template<typename XIN, typename XOUT, bool FIRST, bool LAST>
__global__ __launch_bounds__(512)
void wnet_layer(const XIN* __restrict__ xin, XOUT* __restrict__ xout,
                const float* __restrict__ mask,
                const short* __restrict__ wchi, const short* __restrict__ wclo,
                const float* __restrict__ bc,
                const short* __restrict__ wrhi, const short* __restrict__ wrlo,
                const float* __restrict__ br,
                float* __restrict__ o)
{
    __shared__ __align__(16) short xhi[XR * CPAD];
    __shared__ __align__(16) short xlo[XR * CPAD];

    const int tid = threadIdx.x;
    const int t0  = blockIdx.x * NT;
    const int b   = blockIdx.y;

    // stage x tile, transposed [t][c], hi/lo bf16 split
    const XIN* xg = xin + (size_t)b * C * T;
    for (int idx = tid; idx < C * (XR / 4); idx += 512) {
        int ic  = idx / (XR / 4);
        int tt4 = (idx - ic * (XR / 4)) * 4;
        #pragma unroll
        for (int q = 0; q < 4; ++q) {
            int t = t0 - 2 + tt4 + q;
            float v = (t >= 0 && t < T) ? xld(xg[(size_t)ic * T + t]) : 0.f;
            short h = f2bf(v);
            xhi[(tt4 + q) * CPAD + ic] = h;
            xlo[(tt4 + q) * CPAD + ic] = f2bf(v - bf2f(h));
        }
    }
    __syncthreads();

    const int lane = tid & 63;
    const int wid  = tid >> 6;
    const int wm   = wid & 3;
    const int wn   = wid >> 2;
    const int col  = lane & 15;
    const int sg   = lane >> 4;

    // ---- conv K5 (3-pass split): oc = (h*12+wm*3+j)*16 + 4*sg+i ----
    f32x4 acc[3][2][2];
    #pragma unroll
    for (int j = 0; j < 3; ++j)
    #pragma unroll
    for (int h = 0; h < 2; ++h) {
        f32x4 bv = *reinterpret_cast<const f32x4*>(bc + (h * 12 + wm * 3 + j) * 16 + sg * 4);
        acc[j][h][0] = bv; acc[j][h][1] = bv;
    }

    for (int tap = 0; tap < 5; ++tap) {
        #pragma unroll
        for (int icc = 0; icc < 6; ++icc) {
            short8 bh[2], bl[2];
            #pragma unroll
            for (int p = 0; p < 2; ++p) {
                int off = ((wn * 2 + p) * 16 + col + tap) * CPAD + icc * 32 + sg * 8;
                bh[p] = *reinterpret_cast<const short8*>(&xhi[off]);
                bl[p] = *reinterpret_cast<const short8*>(&xlo[off]);
            }
            #pragma unroll
            for (int h = 0; h < 2; ++h)
            #pragma unroll
            for (int j = 0; j < 3; ++j) {
                const int mt = h * 12 + wm * 3 + j;
                const size_t wo = ((size_t)((tap * 24 + mt) * 6 + icc) * 64 + lane) * 8;
                short8 ah = *reinterpret_cast<const short8*>(wchi + wo);
                short8 al = *reinterpret_cast<const short8*>(wclo + wo);
                #pragma unroll
                for (int p = 0; p < 2; ++p) {
                    acc[j][h][p] = __builtin_amdgcn_mfma_f32_16x16x32_bf16(ah, bh[p], acc[j][h][p], 0, 0, 0);
                    acc[j][h][p] = __builtin_amdgcn_mfma_f32_16x16x32_bf16(al, bh[p], acc[j][h][p], 0, 0, 0);
                    acc[j][h][p] = __builtin_amdgcn_mfma_f32_16x16x32_bf16(ah, bl[p], acc[j][h][p], 0, 0, 0);
                }
            }
        }
    }
    __syncthreads();   // all conv LDS reads done before acts overwrite xhi/xlo

    // ---- gate -> acts hi/lo (reuse xhi/xlo, rows [0,NT)) ----
    #pragma unroll
    for (int j = 0; j < 3; ++j)
    #pragma unroll
    for (int p = 0; p < 2; ++p) {
        const int tt = (wn * 2 + p) * 16 + col;
        const int ch = (wm * 3 + j) * 16 + sg * 4;
        float av[4];
        #pragma unroll
        for (int i = 0; i < 4; ++i)
            av[i] = gatefn(acc[j][0][p][i], acc[j][1][p][i]);
        #pragma unroll
        for (int i2 = 0; i2 < 2; ++i2) {
            short h0 = f2bf(av[i2 * 2]);
            short h1 = f2bf(av[i2 * 2 + 1]);
            short l0 = f2bf(av[i2 * 2]     - bf2f(h0));
            short l1 = f2bf(av[i2 * 2 + 1] - bf2f(h1));
            unsigned ph = (unsigned)(unsigned short)h0 | ((unsigned)(unsigned short)h1 << 16);
            unsigned pl = (unsigned)(unsigned short)l0 | ((unsigned)(unsigned short)l1 << 16);
            *reinterpret_cast<unsigned*>(&xhi[tt * CPAD + ch + i2 * 2]) = ph;
            *reinterpret_cast<unsigned*>(&xlo[tt * CPAD + ch + i2 * 2]) = pl;
        }
    }
    __syncthreads();

    // ---- 1x1 (3-pass split: Wh*ah + Wl*ah + Wh*al) ----
    constexpr int HN = LAST ? 1 : 2;
    f32x4 a2[3][HN][2];
    #pragma unroll
    for (int j = 0; j < 3; ++j)
    #pragma unroll
    for (int h = 0; h < HN; ++h) {
        f32x4 bv = *reinterpret_cast<const f32x4*>(br + (h * 12 + wm * 3 + j) * 16 + sg * 4);
        a2[j][h][0] = bv; a2[j][h][1] = bv;
    }
    #pragma unroll
    for (int icc = 0; icc < 6; ++icc) {
        short8 bah[2], bal[2];
        #pragma unroll
        for (int p = 0; p < 2; ++p) {
            int off = ((wn * 2 + p) * 16 + col) * CPAD + icc * 32 + sg * 8;
            bah[p] = *reinterpret_cast<const short8*>(&xhi[off]);
            bal[p] = *reinterpret_cast<const short8*>(&xlo[off]);
        }
        #pragma unroll
        for (int h = 0; h < HN; ++h)
        #pragma unroll
        for (int j = 0; j < 3; ++j) {
            const int mt = h * 12 + wm * 3 + j;
            const size_t wo = ((size_t)(mt * 6 + icc) * 64 + lane) * 8;
            short8 rh = *reinterpret_cast<const short8*>(wrhi + wo);
            short8 rl = *reinterpret_cast<const short8*>(wrlo + wo);
            #pragma unroll
            for (int p = 0; p < 2; ++p) {
                a2[j][h][p] = __builtin_amdgcn_mfma_f32_16x16x32_bf16(rh, bah[p], a2[j][h][p], 0, 0, 0);
                a2[j][h][p] = __builtin_amdgcn_mfma_f32_16x16x32_bf16(rl, bah[p], a2[j][h][p], 0, 0, 0);
                a2[j][h][p] = __builtin_amdgcn_mfma_f32_16x16x32_bf16(rh, bal[p], a2[j][h][p], 0, 0, 0);
            }
        }
    }

    // ---- epilogue: residual x-update (fp32 master) + skip accumulation ----
    #pragma unroll
    for (int p = 0; p < 2; ++p) {
        const int t = t0 + (wn * 2 + p) * 16 + col;
        const float mv = mask[(size_t)b * T + t];
        #pragma unroll
        for (int j = 0; j < 3; ++j) {
            const int ch = (wm * 3 + j) * 16 + sg * 4;
            float* op = o + ((size_t)b * C + ch) * T + t;
            if constexpr (LAST) {
                #pragma unroll
                for (int i = 0; i < 4; ++i)
                    op[(size_t)i * T] = (op[(size_t)i * T] + a2[j][0][p][i]) * mv;
            } else {
                const XIN* xr = xin + ((size_t)b * C + ch) * T + t;
                XOUT* xw = xout + ((size_t)b * C + ch) * T + t;
                #pragma unroll
                for (int i = 0; i < 4; ++i) {
                    float nx = (xld(xr[(size_t)i * T]) + a2[j][0][p][i]) * mv;
                    if constexpr (std::is_same<XOUT, float>::value)
                        xw[(size_t)i * T] = nx;
                    else
                        xw[(size_t)i * T] = f2bf(nx);
                }
                #pragma unroll
                for (int i = 0; i < 4; ++i) {
                    if constexpr (FIRST) op[(size_t)i * T] = a2[j][1][p][i];
                    else                 op[(size_t)i * T] += a2[j][1][p][i];
                }
            }
        }
    }
}

#define WIN_STRIDE ((size_t)5 * 24 * 6 * 64 * 8)
#define WRS_STRIDE ((size_t)24 * 6 * 64 * 8)

template<typename XT>
static void run_layers(const float* x, const float* mask,
                       const float* b_in, const float* b_rs, const float* b_last,
                       const short* wchi, const short* wclo,
                       const short* wrhi, const short* wrlo,
                       const short* wlhi, const short* wllo,
                       XT* xa, XT* xb, float* o, hipStream_t stream)
{
    dim3 grid(T / NT, BATCH);
    dim3 block(512);
    wnet_layer<float, XT, true, false><<<grid, block, 0, stream>>>(
        x, xa, mask, wchi, wclo, b_in, wrhi, wrlo, b_rs, o);
    const XT* cur = xa;
    for (int i = 1; i < L - 1; ++i) {
        XT* nxt = (i & 1) ? xb : xa;
        wnet_layer<XT, XT, false, false><<<grid, block, 0, stream>>>(
            cur, nxt, mask,
            wchi + (size_t)i * WIN_STRIDE, wclo + (size_t)i * WIN_STRIDE,
            b_in + (size_t)i * 2 * C,
            wrhi + (size_t)i * WRS_STRIDE, wrlo + (size_t)i * WRS_STRIDE,
            b_rs + (size_t)i * 2 * C, o);
        cur = nxt;
    }
    wnet_layer<XT, XT, false, true><<<grid, block, 0, stream>>>(
        cur, (XT*)nullptr, mask,
        wchi + (size_t)(L - 1) * WIN_STRIDE, wclo + (size_t)(L - 1) * WIN_STRIDE,
        b_in + (size_t)(L - 1) * 2 * C,
        wlhi, wllo, b_last, o);
}

extern "C" void kernel_launch(void* const* d_in, const int* in_sizes, int n_in,
                              void* d_out, int out_size, void* d_ws, size_t ws_size,
                              hipStream_t stream)
{
    const float* x      = (const float*)d_in[0];
    const float* mask   = (const float*)d_in[1];
    const float* W_in   = (const float*)d_in[2];
    const float* b_in   = (const float*)d_in[3];
    const float* W_rs   = (const float*)d_in[4];
    const float* b_rs   = (const float*)d_in[5];
    const float* W_last = (const float*)d_in[6];
    const float* b_last = (const float*)d_in[7];
    float* o = (float*)d_out;

    const size_t WIN_N = (size_t)L * WIN_STRIDE;
    const size_t WRS_N = (size_t)(L - 1) * WRS_STRIDE;
    const size_t WL_N  = (size_t)12 * 6 * 64 * 8;
    short* wchi = (short*)d_ws;
    short* wclo = wchi + WIN_N;
    short* wrhi = wclo + WIN_N;
    short* wrlo = wrhi + WRS_N;
    short* wlhi = wrlo + WRS_N;
    short* wllo = wlhi + WL_N;
    char*  xbase = (char*)(wllo + WL_N);
    const size_t fmt_bytes = (WIN_N + WRS_N + WL_N) * 2 * sizeof(short);  // ~28.2 MB
    const size_t xelems = (size_t)BATCH * C * T;

    {
        int tw = (int)(L * 5 * 24 * 6 * 64);
        fmt_win<<<(tw + 255) / 256, 256, 0, stream>>>(W_in, wchi, wclo, tw);
        int tr = (int)((L - 1) * 24 * 6 * 64);
        fmt_w11<<<(tr + 255) / 256, 256, 0, stream>>>(W_rs, wrhi, wrlo, 24, tr);
        int tl = (int)(12 * 6 * 64);
        fmt_w11<<<(tl + 255) / 256, 256, 0, stream>>>(W_last, wlhi, wllo, 12, tl);
    }

    const bool xf32 = ws_size >= fmt_bytes + 2 * xelems * sizeof(float);
    if (xf32) {
        float* xa = (float*)xbase;
        float* xb = xa + xelems;
        run_layers<float>(x, mask, b_in, b_rs, b_last,
                          wchi, wclo, wrhi, wrlo, wlhi, wllo, xa, xb, o, stream);
    } else {
        short* xa = (short*)xbase;   // degraded fallback (small ws)
        short* xb = xa + xelems;
        run_layers<short>(x, mask, b_in, b_rs, b_last,
                          wchi, wclo, wrhi, wrlo, wlhi, wllo, xa, xb, o, stream);
    }
}

// Round 5
// 4403.272 us; speedup vs baseline: 5.4041x; 1.2628x over previous
//
#include <hip/hip_runtime.h>
#include <hip/hip_bf16.h>
#include <type_traits>

#define C 192
#define T 4096
#define L 16
#define BATCH 16
#define NT 128         // t-positions per block
#define XR 136         // x tile rows incl. halo 4+4 (alignment)
#define CPAD 200       // padded channel stride in LDS (shorts)
#define SMEM_BYTES (2 * XR * CPAD * 2)   // xhi + xlo, bf16: 108,800 B

typedef __attribute__((ext_vector_type(8))) short short8;
typedef __attribute__((ext_vector_type(4))) float f32x4;

__device__ __forceinline__ short f2bf(float v) {
    __hip_bfloat16 h = __float2bfloat16(v);
    return *reinterpret_cast<const short*>(&h);
}
__device__ __forceinline__ float bf2f(short s) {
    unsigned u = ((unsigned)(unsigned short)s) << 16;
    float f;
    __builtin_memcpy(&f, &u, 4);
    return f;
}
__device__ __forceinline__ float xld(float v)  { return v; }
__device__ __forceinline__ float xld(short v)  { return bf2f(v); }

__device__ __forceinline__ float gatefn(float x1, float x2) {
    float ax = fabsf(x1);
    float e  = __expf(-2.f * ax);
    float th = __builtin_copysignf((1.f - e) / (1.f + e), x1);
    float sg = 1.f / (1.f + __expf(-x2));
    return th * sg;
}

// ---- weight pre-format with hi/lo bf16 split (Dekker: v-hi exact in fp32) ----
// gid = ((((l*5+tap)*24+mt)*6+icc)*64+lane); oc = mt*16+(lane&15), ic = icc*32+(lane>>4)*8+i
__global__ __launch_bounds__(256)
void fmt_win(const float* __restrict__ W, short* __restrict__ dhi,
             short* __restrict__ dlo, int total) {
    int gid = blockIdx.x * 256 + threadIdx.x;
    if (gid >= total) return;
    int lane = gid & 63; int r = gid >> 6;
    int icc = r % 6; r /= 6;
    int mt  = r % 24; r /= 24;
    int tap = r % 5;  int l = r / 5;
    int oc  = mt * 16 + (lane & 15);
    int ic0 = icc * 32 + (lane >> 4) * 8;
    const float* s = W + ((size_t)((l * 384 + oc) * 192 + ic0)) * 5 + tap;
    short8 vh, vl;
    #pragma unroll
    for (int i = 0; i < 8; ++i) {
        float v = s[(size_t)i * 5];
        short h = f2bf(v);
        vh[i] = h;
        vl[i] = f2bf(v - bf2f(h));
    }
    *reinterpret_cast<short8*>(dhi + (size_t)gid * 8) = vh;
    *reinterpret_cast<short8*>(dlo + (size_t)gid * 8) = vl;
}

// 1x1 weights: gid = ((l*mtc+mt)*6+icc)*64+lane
__global__ __launch_bounds__(256)
void fmt_w11(const float* __restrict__ W, short* __restrict__ dhi,
             short* __restrict__ dlo, int mtc, int total) {
    int gid = blockIdx.x * 256 + threadIdx.x;
    if (gid >= total) return;
    int lane = gid & 63; int r = gid >> 6;
    int icc = r % 6; r /= 6;
    int mt  = r % mtc; int l = r / mtc;
    int oc  = mt * 16 + (lane & 15);
    int ic0 = icc * 32 + (lane >> 4) * 8;
    const float* s = W + (size_t)(l * (mtc * 16) + oc) * 192 + ic0;
    short8 vh, vl;
    #pragma unroll
    for (int i = 0; i < 8; ++i) {
        float v = s[i];
        short h = f2bf(v);
        vh[i] = h;
        vl[i] = f2bf(v - bf2f(h));
    }
    *reinterpret_cast<short8*>(dhi + (size_t)gid * 8) = vh;
    *reinterpret_cast<short8*>(dlo + (size_t)gid * 8) = vl;
}

// ---- fused WaveNet layer, split-bf16, NT=128 (4 nt-subtiles per wave) ----
// 8 waves: wm=wid&3 (3 mt-pairs), wn=wid>>2 (4 nt-tiles each)
template<typename XIN, typename XOUT, bool FIRST, bool LAST>
__global__ __launch_bounds__(512, 2)
void wnet_layer(const XIN* __restrict__ xin, XOUT* __restrict__ xout,
                const float* __restrict__ mask,
                const short* __restrict__ wchi, const short* __restrict__ wclo,
                const float* __restrict__ bc,
                const short* __restrict__ wrhi, const short* __restrict__ wrlo,
                const float* __restrict__ br,
                float* __restrict__ o)
{
    extern __shared__ __align__(16) char smem_raw[];
    short* xhi = reinterpret_cast<short*>(smem_raw);
    short* xlo = xhi + XR * CPAD;   // 54,400 B offset (16B-aligned)

    const int tid = threadIdx.x;
    const int t0  = blockIdx.x * NT;
    const int b   = blockIdx.y;

    // ---- stage x tile, transposed [t][c], hi/lo bf16 split; halo 4 each side ----
    const XIN* xg = xin + (size_t)b * C * T;
    for (int idx = tid; idx < C * (XR / 8); idx += 512) {   // 192*17 tasks, 8 rows each
        int ic = idx / (XR / 8);
        int g  = idx - ic * (XR / 8);
        int ts = t0 - 4 + g * 8;
        const XIN* src = xg + (size_t)ic * T;
        float v[8];
        if (ts >= 0 && ts + 8 <= T) {
            if constexpr (std::is_same<XIN, float>::value) {
                f32x4 u0 = *reinterpret_cast<const f32x4*>(src + ts);
                f32x4 u1 = *reinterpret_cast<const f32x4*>(src + ts + 4);
                #pragma unroll
                for (int q = 0; q < 4; ++q) { v[q] = u0[q]; v[q + 4] = u1[q]; }
            } else {
                short8 s8 = *reinterpret_cast<const short8*>(src + ts);
                #pragma unroll
                for (int q = 0; q < 8; ++q) v[q] = bf2f(s8[q]);
            }
        } else {
            #pragma unroll
            for (int q = 0; q < 8; ++q) {
                int t = ts + q;
                v[q] = (t >= 0 && t < T) ? xld(src[t]) : 0.f;
            }
        }
        #pragma unroll
        for (int q = 0; q < 8; ++q) {
            short h = f2bf(v[q]);
            xhi[(g * 8 + q) * CPAD + ic] = h;
            xlo[(g * 8 + q) * CPAD + ic] = f2bf(v[q] - bf2f(h));
        }
    }
    __syncthreads();

    const int lane = tid & 63;
    const int wid  = tid >> 6;
    const int wm   = wid & 3;
    const int wn   = wid >> 2;
    const int col  = lane & 15;
    const int sg   = lane >> 4;

    // ---- conv K5 (3-pass split): oc = (h*12+wm*3+j)*16 + 4*sg+i ----
    f32x4 acc[3][2][4];
    #pragma unroll
    for (int j = 0; j < 3; ++j)
    #pragma unroll
    for (int h = 0; h < 2; ++h) {
        f32x4 bv = *reinterpret_cast<const f32x4*>(bc + (h * 12 + wm * 3 + j) * 16 + sg * 4);
        #pragma unroll
        for (int p = 0; p < 4; ++p) acc[j][h][p] = bv;
    }

    for (int tap = 0; tap < 5; ++tap) {
        #pragma unroll
        for (int icc = 0; icc < 6; ++icc) {
            short8 bh[4], bl[4];
            #pragma unroll
            for (int p = 0; p < 4; ++p) {
                int off = ((wn * 4 + p) * 16 + col + tap + 2) * CPAD + icc * 32 + sg * 8;
                bh[p] = *reinterpret_cast<const short8*>(&xhi[off]);
                bl[p] = *reinterpret_cast<const short8*>(&xlo[off]);
            }
            #pragma unroll
            for (int h = 0; h < 2; ++h)
            #pragma unroll
            for (int j = 0; j < 3; ++j) {
                const int mt = h * 12 + wm * 3 + j;
                const size_t wo = ((size_t)((tap * 24 + mt) * 6 + icc) * 64 + lane) * 8;
                short8 ah = *reinterpret_cast<const short8*>(wchi + wo);
                short8 al = *reinterpret_cast<const short8*>(wclo + wo);
                #pragma unroll
                for (int p = 0; p < 4; ++p) {
                    acc[j][h][p] = __builtin_amdgcn_mfma_f32_16x16x32_bf16(ah, bh[p], acc[j][h][p], 0, 0, 0);
                    acc[j][h][p] = __builtin_amdgcn_mfma_f32_16x16x32_bf16(al, bh[p], acc[j][h][p], 0, 0, 0);
                    acc[j][h][p] = __builtin_amdgcn_mfma_f32_16x16x32_bf16(ah, bl[p], acc[j][h][p], 0, 0, 0);
                }
            }
        }
    }
    __syncthreads();   // conv LDS reads done before acts overwrite xhi/xlo

    // ---- gate -> acts hi/lo (reuse xhi/xlo, rows [0,NT)) ----
    #pragma unroll
    for (int j = 0; j < 3; ++j)
    #pragma unroll
    for (int p = 0; p < 4; ++p) {
        const int tt = (wn * 4 + p) * 16 + col;
        const int ch = (wm * 3 + j) * 16 + sg * 4;
        float av[4];
        #pragma unroll
        for (int i = 0; i < 4; ++i)
            av[i] = gatefn(acc[j][0][p][i], acc[j][1][p][i]);
        #pragma unroll
        for (int i2 = 0; i2 < 2; ++i2) {
            short h0 = f2bf(av[i2 * 2]);
            short h1 = f2bf(av[i2 * 2 + 1]);
            short l0 = f2bf(av[i2 * 2]     - bf2f(h0));
            short l1 = f2bf(av[i2 * 2 + 1] - bf2f(h1));
            unsigned ph = (unsigned)(unsigned short)h0 | ((unsigned)(unsigned short)h1 << 16);
            unsigned pl = (unsigned)(unsigned short)l0 | ((unsigned)(unsigned short)l1 << 16);
            *reinterpret_cast<unsigned*>(&xhi[tt * CPAD + ch + i2 * 2]) = ph;
            *reinterpret_cast<unsigned*>(&xlo[tt * CPAD + ch + i2 * 2]) = pl;
        }
    }
    __syncthreads();

    // ---- 1x1 (3-pass split: Wh*ah + Wl*ah + Wh*al) ----
    constexpr int HN = LAST ? 1 : 2;
    f32x4 a2[3][HN][4];
    #pragma unroll
    for (int j = 0; j < 3; ++j)
    #pragma unroll
    for (int h = 0; h < HN; ++h) {
        f32x4 bv = *reinterpret_cast<const f32x4*>(br + (h * 12 + wm * 3 + j) * 16 + sg * 4);
        #pragma unroll
        for (int p = 0; p < 4; ++p) a2[j][h][p] = bv;
    }
    #pragma unroll
    for (int icc = 0; icc < 6; ++icc) {
        short8 bah[4], bal[4];
        #pragma unroll
        for (int p = 0; p < 4; ++p) {
            int off = ((wn * 4 + p) * 16 + col) * CPAD + icc * 32 + sg * 8;
            bah[p] = *reinterpret_cast<const short8*>(&xhi[off]);
            bal[p] = *reinterpret_cast<const short8*>(&xlo[off]);
        }
        #pragma unroll
        for (int h = 0; h < HN; ++h)
        #pragma unroll
        for (int j = 0; j < 3; ++j) {
            const int mt = h * 12 + wm * 3 + j;
            const size_t wo = ((size_t)(mt * 6 + icc) * 64 + lane) * 8;
            short8 rh = *reinterpret_cast<const short8*>(wrhi + wo);
            short8 rl = *reinterpret_cast<const short8*>(wrlo + wo);
            #pragma unroll
            for (int p = 0; p < 4; ++p) {
                a2[j][h][p] = __builtin_amdgcn_mfma_f32_16x16x32_bf16(rh, bah[p], a2[j][h][p], 0, 0, 0);
                a2[j][h][p] = __builtin_amdgcn_mfma_f32_16x16x32_bf16(rl, bah[p], a2[j][h][p], 0, 0, 0);
                a2[j][h][p] = __builtin_amdgcn_mfma_f32_16x16x32_bf16(rh, bal[p], a2[j][h][p], 0, 0, 0);
            }
        }
    }

    // ---- epilogue: residual x-update (fp32 master) + skip accumulation ----
    #pragma unroll
    for (int p = 0; p < 4; ++p) {
        const int t = t0 + (wn * 4 + p) * 16 + col;
        const float mv = mask[(size_t)b * T + t];
        #pragma unroll
        for (int j = 0; j < 3; ++j) {
            const int ch = (wm * 3 + j) * 16 + sg * 4;
            float* op = o + ((size_t)b * C + ch) * T + t;
            if constexpr (LAST) {
                #pragma unroll
                for (int i = 0; i < 4; ++i)
                    op[(size_t)i * T] = (op[(size_t)i * T] + a2[j][0][p][i]) * mv;
            } else {
                const XIN* xr = xin + ((size_t)b * C + ch) * T + t;
                XOUT* xw = xout + ((size_t)b * C + ch) * T + t;
                #pragma unroll
                for (int i = 0; i < 4; ++i) {
                    float nx = (xld(xr[(size_t)i * T]) + a2[j][0][p][i]) * mv;
                    if constexpr (std::is_same<XOUT, float>::value)
                        xw[(size_t)i * T] = nx;
                    else
                        xw[(size_t)i * T] = f2bf(nx);
                }
                #pragma unroll
                for (int i = 0; i < 4; ++i) {
                    if constexpr (FIRST) op[(size_t)i * T] = a2[j][1][p][i];
                    else                 op[(size_t)i * T] += a2[j][1][p][i];
                }
            }
        }
    }
}

#define WIN_STRIDE ((size_t)5 * 24 * 6 * 64 * 8)
#define WRS_STRIDE ((size_t)24 * 6 * 64 * 8)

template<typename XT>
static void run_layers(const float* x, const float* mask,
                       const float* b_in, const float* b_rs, const float* b_last,
                       const short* wchi, const short* wclo,
                       const short* wrhi, const short* wrlo,
                       const short* wlhi, const short* wllo,
                       XT* xa, XT* xb, float* o, hipStream_t stream)
{
    // raise dynamic-LDS cap for the 3 instantiations (non-stream call; capture-safe)
    (void)hipFuncSetAttribute(reinterpret_cast<const void*>(&wnet_layer<float, XT, true, false>),
                              hipFuncAttributeMaxDynamicSharedMemorySize, SMEM_BYTES);
    (void)hipFuncSetAttribute(reinterpret_cast<const void*>(&wnet_layer<XT, XT, false, false>),
                              hipFuncAttributeMaxDynamicSharedMemorySize, SMEM_BYTES);
    (void)hipFuncSetAttribute(reinterpret_cast<const void*>(&wnet_layer<XT, XT, false, true>),
                              hipFuncAttributeMaxDynamicSharedMemorySize, SMEM_BYTES);

    dim3 grid(T / NT, BATCH);
    dim3 block(512);
    wnet_layer<float, XT, true, false><<<grid, block, SMEM_BYTES, stream>>>(
        x, xa, mask, wchi, wclo, b_in, wrhi, wrlo, b_rs, o);
    const XT* cur = xa;
    for (int i = 1; i < L - 1; ++i) {
        XT* nxt = (i & 1) ? xb : xa;
        wnet_layer<XT, XT, false, false><<<grid, block, SMEM_BYTES, stream>>>(
            cur, nxt, mask,
            wchi + (size_t)i * WIN_STRIDE, wclo + (size_t)i * WIN_STRIDE,
            b_in + (size_t)i * 2 * C,
            wrhi + (size_t)i * WRS_STRIDE, wrlo + (size_t)i * WRS_STRIDE,
            b_rs + (size_t)i * 2 * C, o);
        cur = nxt;
    }
    wnet_layer<XT, XT, false, true><<<grid, block, SMEM_BYTES, stream>>>(
        cur, (XT*)nullptr, mask,
        wchi + (size_t)(L - 1) * WIN_STRIDE, wclo + (size_t)(L - 1) * WIN_STRIDE,
        b_in + (size_t)(L - 1) * 2 * C,
        wlhi, wllo, b_last, o);
}

extern "C" void kernel_launch(void* const* d_in, const int* in_sizes, int n_in,
                              void* d_out, int out_size, void* d_ws, size_t ws_size,
                              hipStream_t stream)
{
    const float* x      = (const float*)d_in[0];
    const float* mask   = (const float*)d_in[1];
    const float* W_in   = (const float*)d_in[2];
    const float* b_in   = (const float*)d_in[3];
    const float* W_rs   = (const float*)d_in[4];
    const float* b_rs   = (const float*)d_in[5];
    const float* W_last = (const float*)d_in[6];
    const float* b_last = (const float*)d_in[7];
    float* o = (float*)d_out;

    const size_t WIN_N = (size_t)L * WIN_STRIDE;
    const size_t WRS_N = (size_t)(L - 1) * WRS_STRIDE;
    const size_t WL_N  = (size_t)12 * 6 * 64 * 8;
    short* wchi = (short*)d_ws;
    short* wclo = wchi + WIN_N;
    short* wrhi = wclo + WIN_N;
    short* wrlo = wrhi + WRS_N;
    short* wlhi = wrlo + WRS_N;
    short* wllo = wlhi + WL_N;
    char*  xbase = (char*)(wllo + WL_N);
    const size_t fmt_bytes = (WIN_N + WRS_N + WL_N) * 2 * sizeof(short);  // ~28.2 MB
    const size_t xelems = (size_t)BATCH * C * T;

    {
        int tw = (int)(L * 5 * 24 * 6 * 64);
        fmt_win<<<(tw + 255) / 256, 256, 0, stream>>>(W_in, wchi, wclo, tw);
        int tr = (int)((L - 1) * 24 * 6 * 64);
        fmt_w11<<<(tr + 255) / 256, 256, 0, stream>>>(W_rs, wrhi, wrlo, 24, tr);
        int tl = (int)(12 * 6 * 64);
        fmt_w11<<<(tl + 255) / 256, 256, 0, stream>>>(W_last, wlhi, wllo, 12, tl);
    }

    const bool xf32 = ws_size >= fmt_bytes + 2 * xelems * sizeof(float);
    if (xf32) {
        float* xa = (float*)xbase;
        float* xb = xa + xelems;
        run_layers<float>(x, mask, b_in, b_rs, b_last,
                          wchi, wclo, wrhi, wrlo, wlhi, wllo, xa, xb, o, stream);
    } else {
        short* xa = (short*)xbase;   // degraded fallback (small ws)
        short* xb = xa + xelems;
        run_layers<short>(x, mask, b_in, b_rs, b_last,
                          wchi, wclo, wrhi, wrlo, wlhi, wllo, xa, xb, o, stream);
    }
}

// Round 6
// 3197.999 us; speedup vs baseline: 7.4409x; 1.3769x over previous
//
#include <hip/hip_runtime.h>
#include <hip/hip_bf16.h>

#define C 192
#define T 4096
#define L 16
#define BATCH 16
#define NT 128         // t-positions per block
#define XR 136         // x tile rows incl. halo 4+4
#define CPAD 200       // padded channel stride in LDS (shorts) -> 400B rows
#define SMEM_BYTES (2 * XR * CPAD * 2)   // xhi + xlo: 108,800 B

typedef __attribute__((ext_vector_type(8))) short short8;
typedef __attribute__((ext_vector_type(4))) short short4v;
typedef __attribute__((ext_vector_type(4))) float f32x4;

__device__ __forceinline__ short f2bf(float v) {
    __hip_bfloat16 h = __float2bfloat16(v);
    return *reinterpret_cast<const short*>(&h);
}
__device__ __forceinline__ float bf2f(short s) {
    unsigned u = ((unsigned)(unsigned short)s) << 16;
    float f;
    __builtin_memcpy(&f, &u, 4);
    return f;
}

__device__ __forceinline__ float gatefn(float x1, float x2) {
    float ax = fabsf(x1);
    float e  = __expf(-2.f * ax);
    float th = __builtin_copysignf((1.f - e) / (1.f + e), x1);
    float sg = 1.f / (1.f + __expf(-x2));
    return th * sg;
}

// ---- weight pre-format with hi/lo bf16 split (Dekker: v-hi exact in fp32) ----
__global__ __launch_bounds__(256)
void fmt_win(const float* __restrict__ W, short* __restrict__ dhi,
             short* __restrict__ dlo, int total) {
    int gid = blockIdx.x * 256 + threadIdx.x;
    if (gid >= total) return;
    int lane = gid & 63; int r = gid >> 6;
    int icc = r % 6; r /= 6;
    int mt  = r % 24; r /= 24;
    int tap = r % 5;  int l = r / 5;
    int oc  = mt * 16 + (lane & 15);
    int ic0 = icc * 32 + (lane >> 4) * 8;
    const float* s = W + ((size_t)((l * 384 + oc) * 192 + ic0)) * 5 + tap;
    short8 vh, vl;
    #pragma unroll
    for (int i = 0; i < 8; ++i) {
        float v = s[(size_t)i * 5];
        short h = f2bf(v);
        vh[i] = h;
        vl[i] = f2bf(v - bf2f(h));
    }
    *reinterpret_cast<short8*>(dhi + (size_t)gid * 8) = vh;
    *reinterpret_cast<short8*>(dlo + (size_t)gid * 8) = vl;
}

__global__ __launch_bounds__(256)
void fmt_w11(const float* __restrict__ W, short* __restrict__ dhi,
             short* __restrict__ dlo, int mtc, int total) {
    int gid = blockIdx.x * 256 + threadIdx.x;
    if (gid >= total) return;
    int lane = gid & 63; int r = gid >> 6;
    int icc = r % 6; r /= 6;
    int mt  = r % mtc; int l = r / mtc;
    int oc  = mt * 16 + (lane & 15);
    int ic0 = icc * 32 + (lane >> 4) * 8;
    const float* s = W + (size_t)(l * (mtc * 16) + oc) * 192 + ic0;
    short8 vh, vl;
    #pragma unroll
    for (int i = 0; i < 8; ++i) {
        float v = s[i];
        short h = f2bf(v);
        vh[i] = h;
        vl[i] = f2bf(v - bf2f(h));
    }
    *reinterpret_cast<short8*>(dhi + (size_t)gid * 8) = vh;
    *reinterpret_cast<short8*>(dlo + (size_t)gid * 8) = vl;
}

// ---- one-time transpose+split: x fp32 [b][c][t] -> hi/lo bf16 planes [b][t][c] ----
__global__ __launch_bounds__(256)
void xpose(const float* __restrict__ x, short* __restrict__ xh, short* __restrict__ xl)
{
    __shared__ float tile[C][65];
    const int t0 = blockIdx.x * 64;
    const int b  = blockIdx.y;
    const float* xg = x + (size_t)b * C * T;
    for (int idx = threadIdx.x; idx < C * 16; idx += 256) {
        int ch = idx & 15, c = idx >> 4;
        f32x4 v = *reinterpret_cast<const f32x4*>(xg + (size_t)c * T + t0 + ch * 4);
        #pragma unroll
        for (int q = 0; q < 4; ++q) tile[c][ch * 4 + q] = v[q];
    }
    __syncthreads();
    for (int idx = threadIdx.x; idx < 64 * 24; idx += 256) {
        int cc = idx % 24, t = idx / 24;
        short8 h8, l8;
        #pragma unroll
        for (int i = 0; i < 8; ++i) {
            float v = tile[cc * 8 + i][t];
            short h = f2bf(v);
            h8[i] = h;
            l8[i] = f2bf(v - bf2f(h));
        }
        size_t off = (size_t)b * T * C + (size_t)(t0 + t) * C + cc * 8;
        *reinterpret_cast<short8*>(xh + off) = h8;
        *reinterpret_cast<short8*>(xl + off) = l8;
    }
}

// ---- fused WaveNet layer: x master is hi/lo bf16 [b][t][c] planes in ws ----
// 8 waves: wm=wid&3 (3 mt-pairs), wn=wid>>2 (4 nt-tiles each)
template<bool FIRST, bool LAST>
__global__ __launch_bounds__(512, 2)
void wnet_layer(const short* __restrict__ xhin, const short* __restrict__ xlin,
                short* __restrict__ xhout, short* __restrict__ xlout,
                const float* __restrict__ mask,
                const short* __restrict__ wchi, const short* __restrict__ wclo,
                const float* __restrict__ bc,
                const short* __restrict__ wrhi, const short* __restrict__ wrlo,
                const float* __restrict__ br,
                float* __restrict__ o)
{
    extern __shared__ __align__(16) char smem_raw[];
    short* xhi = reinterpret_cast<short*>(smem_raw);
    short* xlo = xhi + XR * CPAD;

    const int tid = threadIdx.x;
    const int t0  = blockIdx.x * NT;
    const int b   = blockIdx.y;

    // ---- stage: pure 16B vector copies, no conversion, no transpose ----
    {
        const short* gh = xhin + (size_t)b * T * C;
        const short* gl = xlin + (size_t)b * T * C;
        for (int idx = tid; idx < 2 * XR * 24; idx += 512) {
            int chunk = idx % 24;
            int r     = (idx / 24) % XR;
            int plane = idx / (24 * XR);
            int t = t0 - 4 + r;
            short8 v = {};
            if (t >= 0 && t < T)
                v = *reinterpret_cast<const short8*>(
                        (plane ? gl : gh) + (size_t)t * C + chunk * 8);
            *reinterpret_cast<short8*>((plane ? xlo : xhi) + r * CPAD + chunk * 8) = v;
        }
    }
    __syncthreads();

    const int lane = tid & 63;
    const int wid  = tid >> 6;
    const int wm   = wid & 3;
    const int wn   = wid >> 2;
    const int col  = lane & 15;
    const int sg   = lane >> 4;

    // ---- conv K5 (3-pass Dekker split): oc = (h*12+wm*3+j)*16 + 4*sg+i ----
    f32x4 acc[3][2][4];
    #pragma unroll
    for (int j = 0; j < 3; ++j)
    #pragma unroll
    for (int h = 0; h < 2; ++h) {
        f32x4 bv = *reinterpret_cast<const f32x4*>(bc + (h * 12 + wm * 3 + j) * 16 + sg * 4);
        #pragma unroll
        for (int p = 0; p < 4; ++p) acc[j][h][p] = bv;
    }

    for (int tap = 0; tap < 5; ++tap) {
        #pragma unroll
        for (int icc = 0; icc < 6; ++icc) {
            short8 bh[4], bl[4];
            #pragma unroll
            for (int p = 0; p < 4; ++p) {
                int off = ((wn * 4 + p) * 16 + col + tap + 2) * CPAD + icc * 32 + sg * 8;
                bh[p] = *reinterpret_cast<const short8*>(&xhi[off]);
                bl[p] = *reinterpret_cast<const short8*>(&xlo[off]);
            }
            #pragma unroll
            for (int h = 0; h < 2; ++h)
            #pragma unroll
            for (int j = 0; j < 3; ++j) {
                const int mt = h * 12 + wm * 3 + j;
                const size_t wo = ((size_t)((tap * 24 + mt) * 6 + icc) * 64 + lane) * 8;
                short8 ah = *reinterpret_cast<const short8*>(wchi + wo);
                short8 al = *reinterpret_cast<const short8*>(wclo + wo);
                #pragma unroll
                for (int p = 0; p < 4; ++p) {
                    acc[j][h][p] = __builtin_amdgcn_mfma_f32_16x16x32_bf16(ah, bh[p], acc[j][h][p], 0, 0, 0);
                    acc[j][h][p] = __builtin_amdgcn_mfma_f32_16x16x32_bf16(al, bh[p], acc[j][h][p], 0, 0, 0);
                    acc[j][h][p] = __builtin_amdgcn_mfma_f32_16x16x32_bf16(ah, bl[p], acc[j][h][p], 0, 0, 0);
                }
            }
        }
    }

    // ---- residual x pre-read from LDS (before acts overwrite) ----
    float xres[3][4][4];
    if constexpr (!LAST) {
        #pragma unroll
        for (int p = 0; p < 4; ++p) {
            const int row = (wn * 4 + p) * 16 + col + 4;
            #pragma unroll
            for (int j = 0; j < 3; ++j) {
                const int ch = (wm * 3 + j) * 16 + sg * 4;
                short4v h4 = *reinterpret_cast<const short4v*>(&xhi[row * CPAD + ch]);
                short4v l4 = *reinterpret_cast<const short4v*>(&xlo[row * CPAD + ch]);
                #pragma unroll
                for (int i = 0; i < 4; ++i) xres[j][p][i] = bf2f(h4[i]) + bf2f(l4[i]);
            }
        }
    }
    __syncthreads();   // conv + residual LDS reads done before acts overwrite

    // ---- gate -> acts hi/lo (reuse xhi/xlo, rows [0,NT)) ----
    #pragma unroll
    for (int j = 0; j < 3; ++j)
    #pragma unroll
    for (int p = 0; p < 4; ++p) {
        const int tt = (wn * 4 + p) * 16 + col;
        const int ch = (wm * 3 + j) * 16 + sg * 4;
        float av[4];
        #pragma unroll
        for (int i = 0; i < 4; ++i)
            av[i] = gatefn(acc[j][0][p][i], acc[j][1][p][i]);
        #pragma unroll
        for (int i2 = 0; i2 < 2; ++i2) {
            short h0 = f2bf(av[i2 * 2]);
            short h1 = f2bf(av[i2 * 2 + 1]);
            short l0 = f2bf(av[i2 * 2]     - bf2f(h0));
            short l1 = f2bf(av[i2 * 2 + 1] - bf2f(h1));
            unsigned ph = (unsigned)(unsigned short)h0 | ((unsigned)(unsigned short)h1 << 16);
            unsigned pl = (unsigned)(unsigned short)l0 | ((unsigned)(unsigned short)l1 << 16);
            *reinterpret_cast<unsigned*>(&xhi[tt * CPAD + ch + i2 * 2]) = ph;
            *reinterpret_cast<unsigned*>(&xlo[tt * CPAD + ch + i2 * 2]) = pl;
        }
    }
    __syncthreads();

    // ---- 1x1 (3-pass split: Wh*ah + Wl*ah + Wh*al) ----
    constexpr int HN = LAST ? 1 : 2;
    f32x4 a2[3][HN][4];
    #pragma unroll
    for (int j = 0; j < 3; ++j)
    #pragma unroll
    for (int h = 0; h < HN; ++h) {
        f32x4 bv = *reinterpret_cast<const f32x4*>(br + (h * 12 + wm * 3 + j) * 16 + sg * 4);
        #pragma unroll
        for (int p = 0; p < 4; ++p) a2[j][h][p] = bv;
    }
    #pragma unroll
    for (int icc = 0; icc < 6; ++icc) {
        short8 bah[4], bal[4];
        #pragma unroll
        for (int p = 0; p < 4; ++p) {
            int off = ((wn * 4 + p) * 16 + col) * CPAD + icc * 32 + sg * 8;
            bah[p] = *reinterpret_cast<const short8*>(&xhi[off]);
            bal[p] = *reinterpret_cast<const short8*>(&xlo[off]);
        }
        #pragma unroll
        for (int h = 0; h < HN; ++h)
        #pragma unroll
        for (int j = 0; j < 3; ++j) {
            const int mt = h * 12 + wm * 3 + j;
            const size_t wo = ((size_t)(mt * 6 + icc) * 64 + lane) * 8;
            short8 rh = *reinterpret_cast<const short8*>(wrhi + wo);
            short8 rl = *reinterpret_cast<const short8*>(wrlo + wo);
            #pragma unroll
            for (int p = 0; p < 4; ++p) {
                a2[j][h][p] = __builtin_amdgcn_mfma_f32_16x16x32_bf16(rh, bah[p], a2[j][h][p], 0, 0, 0);
                a2[j][h][p] = __builtin_amdgcn_mfma_f32_16x16x32_bf16(rl, bah[p], a2[j][h][p], 0, 0, 0);
                a2[j][h][p] = __builtin_amdgcn_mfma_f32_16x16x32_bf16(rh, bal[p], a2[j][h][p], 0, 0, 0);
            }
        }
    }

    // ---- epilogue ----
    #pragma unroll
    for (int p = 0; p < 4; ++p) {
        const int tt = (wn * 4 + p) * 16 + col;
        const int t  = t0 + tt;
        const float mv = mask[(size_t)b * T + t];
        #pragma unroll
        for (int j = 0; j < 3; ++j) {
            const int ch = (wm * 3 + j) * 16 + sg * 4;
            float* op = o + ((size_t)b * C + ch) * T + t;
            if constexpr (LAST) {
                #pragma unroll
                for (int i = 0; i < 4; ++i)
                    op[(size_t)i * T] = (op[(size_t)i * T] + a2[j][0][p][i]) * mv;
            } else {
                short4v h4, l4;
                #pragma unroll
                for (int i = 0; i < 4; ++i) {
                    float nx = (xres[j][p][i] + a2[j][0][p][i]) * mv;
                    short h = f2bf(nx);
                    h4[i] = h;
                    l4[i] = f2bf(nx - bf2f(h));
                }
                size_t off = (size_t)b * T * C + (size_t)t * C + ch;
                *reinterpret_cast<short4v*>(xhout + off) = h4;
                *reinterpret_cast<short4v*>(xlout + off) = l4;
                #pragma unroll
                for (int i = 0; i < 4; ++i) {
                    if constexpr (FIRST) op[(size_t)i * T] = a2[j][1][p][i];
                    else                 op[(size_t)i * T] += a2[j][1][p][i];
                }
            }
        }
    }
}

#define WIN_STRIDE ((size_t)5 * 24 * 6 * 64 * 8)
#define WRS_STRIDE ((size_t)24 * 6 * 64 * 8)

extern "C" void kernel_launch(void* const* d_in, const int* in_sizes, int n_in,
                              void* d_out, int out_size, void* d_ws, size_t ws_size,
                              hipStream_t stream)
{
    const float* x      = (const float*)d_in[0];
    const float* mask   = (const float*)d_in[1];
    const float* W_in   = (const float*)d_in[2];
    const float* b_in   = (const float*)d_in[3];
    const float* W_rs   = (const float*)d_in[4];
    const float* b_rs   = (const float*)d_in[5];
    const float* W_last = (const float*)d_in[6];
    const float* b_last = (const float*)d_in[7];
    float* o = (float*)d_out;

    const size_t WIN_N = (size_t)L * WIN_STRIDE;
    const size_t WRS_N = (size_t)(L - 1) * WRS_STRIDE;
    const size_t WL_N  = (size_t)12 * 6 * 64 * 8;
    const size_t P     = (size_t)BATCH * T * C;      // plane elems (shorts)
    short* wchi = (short*)d_ws;
    short* wclo = wchi + WIN_N;
    short* wrhi = wclo + WIN_N;
    short* wrlo = wrhi + WRS_N;
    short* wlhi = wrlo + WRS_N;
    short* wllo = wlhi + WL_N;
    short* xah  = wllo + WL_N;
    short* xal  = xah + P;
    short* xbh  = xal + P;
    short* xbl  = xbh + P;

    {
        int tw = (int)(L * 5 * 24 * 6 * 64);
        fmt_win<<<(tw + 255) / 256, 256, 0, stream>>>(W_in, wchi, wclo, tw);
        int tr = (int)((L - 1) * 24 * 6 * 64);
        fmt_w11<<<(tr + 255) / 256, 256, 0, stream>>>(W_rs, wrhi, wrlo, 24, tr);
        int tl = (int)(12 * 6 * 64);
        fmt_w11<<<(tl + 255) / 256, 256, 0, stream>>>(W_last, wlhi, wllo, 12, tl);
        xpose<<<dim3(T / 64, BATCH), 256, 0, stream>>>(x, xah, xal);
    }

    (void)hipFuncSetAttribute(reinterpret_cast<const void*>(&wnet_layer<true, false>),
                              hipFuncAttributeMaxDynamicSharedMemorySize, SMEM_BYTES);
    (void)hipFuncSetAttribute(reinterpret_cast<const void*>(&wnet_layer<false, false>),
                              hipFuncAttributeMaxDynamicSharedMemorySize, SMEM_BYTES);
    (void)hipFuncSetAttribute(reinterpret_cast<const void*>(&wnet_layer<false, true>),
                              hipFuncAttributeMaxDynamicSharedMemorySize, SMEM_BYTES);

    dim3 grid(T / NT, BATCH);
    dim3 block(512);

    short* curh = xah; short* curl = xal;
    short* nxth = xbh; short* nxtl = xbl;

    wnet_layer<true, false><<<grid, block, SMEM_BYTES, stream>>>(
        curh, curl, nxth, nxtl, mask,
        wchi, wclo, b_in, wrhi, wrlo, b_rs, o);
    { short* t1 = curh; curh = nxth; nxth = t1;
      short* t2 = curl; curl = nxtl; nxtl = t2; }

    for (int i = 1; i < L - 1; ++i) {
        wnet_layer<false, false><<<grid, block, SMEM_BYTES, stream>>>(
            curh, curl, nxth, nxtl, mask,
            wchi + (size_t)i * WIN_STRIDE, wclo + (size_t)i * WIN_STRIDE,
            b_in + (size_t)i * 2 * C,
            wrhi + (size_t)i * WRS_STRIDE, wrlo + (size_t)i * WRS_STRIDE,
            b_rs + (size_t)i * 2 * C, o);
        { short* t1 = curh; curh = nxth; nxth = t1;
          short* t2 = curl; curl = nxtl; nxtl = t2; }
    }

    wnet_layer<false, true><<<grid, block, SMEM_BYTES, stream>>>(
        curh, curl, nullptr, nullptr, mask,
        wchi + (size_t)(L - 1) * WIN_STRIDE, wclo + (size_t)(L - 1) * WIN_STRIDE,
        b_in + (size_t)(L - 1) * 2 * C,
        wlhi, wllo, b_last, o);
}